// Round 5
// baseline (577.025 us; speedup 1.0000x reference)
//
#include <hip/hip_runtime.h>

#define D 64
#define SH 7            // 128 cols per bucket
#define CPB 128         // cols per bucket
#define CH 4096         // edges per block in bucketing kernels

// ---------- bucket-sort path ----------

__global__ __launch_bounds__(256) void bucket_totals(
    const int* __restrict__ es, int* __restrict__ btotal, int NB, int E) {
  __shared__ int h[1024];
  for (int i = threadIdx.x; i < 1024; i += 256) h[i] = 0;
  __syncthreads();
  int e0 = blockIdx.x * CH + threadIdx.x;
#pragma unroll
  for (int j = 0; j < 16; j++) {
    int e = e0 + j * 256;
    if (e < E) atomicAdd(&h[es[e] >> SH], 1);
  }
  __syncthreads();
  for (int i = threadIdx.x; i < NB; i += 256) {
    int v = h[i];
    if (v) atomicAdd(&btotal[i], v);
  }
}

// single block: exclusive scan of NB (<=1024) bucket totals
__global__ __launch_bounds__(256) void scan_buckets(
    const int* __restrict__ btotal, int* __restrict__ bbase,
    int* __restrict__ gcursor, int NB, int E) {
  __shared__ int lds[256];
  int t = threadIdx.x;
  int v[4], s = 0;
#pragma unroll
  for (int i = 0; i < 4; i++) {
    int idx = t * 4 + i;
    v[i] = (idx < NB) ? btotal[idx] : 0;
    s += v[i];
  }
  lds[t] = s;
  __syncthreads();
  for (int off = 1; off < 256; off <<= 1) {
    int val = (t >= off) ? lds[t - off] : 0;
    __syncthreads();
    lds[t] += val;
    __syncthreads();
  }
  int run = (t == 0) ? 0 : lds[t - 1];
#pragma unroll
  for (int i = 0; i < 4; i++) {
    int idx = t * 4 + i;
    if (idx < NB) { bbase[idx] = run; gcursor[idx] = run; }
    run += v[i];
  }
  if (t == 0) bbase[NB] = E;
}

__global__ __launch_bounds__(256) void bucket_scatter(
    const int* __restrict__ es, int* __restrict__ gcursor,
    int* __restrict__ packed, int NB, int E) {
  __shared__ int lhist[1024];   // hist -> local start -> intra-block cursor
  __shared__ int delta[1024];   // global_base - local_start per bucket
  __shared__ int sctmp[256];
  __shared__ int staged[CH];
  __shared__ int destg[CH];
  int t = threadIdx.x;
  for (int i = t; i < 1024; i += 256) lhist[i] = 0;
  __syncthreads();
  int base_e = blockIdx.x * CH;
  // pass A: local histogram
#pragma unroll
  for (int j = 0; j < 16; j++) {
    int e = base_e + t + j * 256;
    if (e < E) atomicAdd(&lhist[es[e] >> SH], 1);
  }
  __syncthreads();
  // local exclusive scan over 1024 buckets (thread owns 4)
  int v[4], s = 0;
#pragma unroll
  for (int i = 0; i < 4; i++) { v[i] = lhist[t * 4 + i]; s += v[i]; }
  sctmp[t] = s;
  __syncthreads();
  for (int off = 1; off < 256; off <<= 1) {
    int val = (t >= off) ? sctmp[t - off] : 0;
    __syncthreads();
    sctmp[t] += val;
    __syncthreads();
  }
  int run = (t == 0) ? 0 : sctmp[t - 1];
  int lstart4[4];
#pragma unroll
  for (int i = 0; i < 4; i++) { lstart4[i] = run; run += v[i]; }
  __syncthreads();  // all reads of lhist done before overwrite
  // reserve global space per bucket; set up cursor + delta
#pragma unroll
  for (int i = 0; i < 4; i++) {
    int b = t * 4 + i;
    int gb = (b < NB && v[i] > 0) ? atomicAdd(&gcursor[b], v[i]) : 0;
    delta[b] = gb - lstart4[i];
    lhist[b] = lstart4[i];
  }
  __syncthreads();
  // pass B: rank + stage
#pragma unroll
  for (int j = 0; j < 16; j++) {
    int e = base_e + t + j * 256;
    if (e < E) {
      int c = es[e];
      int r = es[E + e];
      int b = c >> SH;
      int rank = atomicAdd(&lhist[b], 1);
      staged[rank] = (r << SH) | (c & (CPB - 1));
      destg[rank] = delta[b] + rank;
    }
  }
  __syncthreads();
  // coalesced run-contiguous write-out
  int nloc = min(CH, E - base_e);
  for (int i = t; i < nloc; i += 256) packed[destg[i]] = staged[i];
}

// one block per bucket: LDS accumulators for 128 cols x 64 feats
__global__ __launch_bounds__(256) void bucket_reduce(
    const float* __restrict__ x, const int* __restrict__ packed,
    const int* __restrict__ bbase, float* __restrict__ out, int N) {
  __shared__ float acc[CPB * D];  // 32 KB
  __shared__ int cntL[CPB];
  int t = threadIdx.x;
  for (int i = t; i < CPB * D; i += 256) acc[i] = 0.f;
  for (int i = t; i < CPB; i += 256) cntL[i] = 0;
  __syncthreads();
  int b = blockIdx.x;
  int s = bbase[b], epos = bbase[b + 1];
  int lane = t & 63, w = t >> 6;
  for (int base = s + w * 4; base < epos; base += 16) {
#pragma unroll
    for (int u = 0; u < 4; u++) {
      int idx = base + u;
      if (idx < epos) {
        int p = packed[idx];
        int c = p & (CPB - 1);
        int r = p >> SH;
        float val = x[(size_t)r * D + lane];
        atomicAdd(&acc[c * D + lane], val);
        if (lane == 0) atomicAdd(&cntL[c], 1);
      }
    }
  }
  __syncthreads();
  int cbase = b << SH;
  for (int i = t; i < CPB * D; i += 256) {
    int c = i >> 6, d = i & 63;
    int gc = cbase + c;
    if (gc < N) {
      int cnt = cntL[c];
      float inv = 1.0f / (float)(cnt > 0 ? cnt : 1);
      out[(size_t)gc * 2 * D + d] = acc[i] * inv;
      out[(size_t)gc * 2 * D + D + d] = (cnt > 0) ? x[(size_t)gc * D + d] : 0.f;
    }
  }
}

// ---------- fallback atomic path (only if ws too small) ----------

__global__ __launch_bounds__(256) void edge_scatter_atomic(
    const int* __restrict__ es, const float* __restrict__ x,
    float* __restrict__ out, int* __restrict__ count, int E) {
  int gid = blockIdx.x * blockDim.x + threadIdx.x;
  int e = gid >> 6;
  int lane = gid & 63;
  if (e >= E) return;
  int c = es[e];
  int r = es[E + e];
  if (lane == 0) atomicAdd(&count[c], 1);
  float v = x[(size_t)r * D + lane];
  unsafeAtomicAdd(&out[(size_t)c * 2 * D + lane], v);
}

__global__ __launch_bounds__(256) void finalize_atomic(
    const float* __restrict__ x, float* __restrict__ out,
    const int* __restrict__ count, int N) {
  int gid = blockIdx.x * blockDim.x + threadIdx.x;
  int node = gid >> 5;
  int j4 = gid & 31;
  if (node >= N) return;
  int cnt = count[node];
  float4* out4 = (float4*)(out + (size_t)node * 2 * D);
  if (j4 < 16) {
    float4 s = out4[j4];
    float inv = 1.0f / (float)(cnt > 0 ? cnt : 1);
    s.x *= inv; s.y *= inv; s.z *= inv; s.w *= inv;
    out4[j4] = s;
  } else {
    float4 v;
    if (cnt > 0) {
      const float4* x4 = (const float4*)(x + (size_t)node * D);
      v = x4[j4 - 16];
    } else {
      v = make_float4(0.f, 0.f, 0.f, 0.f);
    }
    out4[j4] = v;
  }
}

extern "C" void kernel_launch(void* const* d_in, const int* in_sizes, int n_in,
                              void* d_out, int out_size, void* d_ws, size_t ws_size,
                              hipStream_t stream) {
  const float* x = (const float*)d_in[0];
  const int* es = (const int*)d_in[1];
  int N = in_sizes[0] / D;
  int E = in_sizes[1] / 2;
  float* out = (float*)d_out;

  int NB = (N + CPB - 1) >> SH;
  size_t need = (size_t)(1024 + 1056 + 1024 + E) * sizeof(int);
  if (NB > 1024 || ws_size < need) {
    int* count = (int*)d_ws;
    hipMemsetAsync(count, 0, (size_t)N * sizeof(int), stream);
    hipMemsetAsync(out, 0, (size_t)N * 2 * D * sizeof(float), stream);
    long long t1 = (long long)E * 64;
    edge_scatter_atomic<<<(int)((t1 + 255) / 256), 256, 0, stream>>>(es, x, out, count, E);
    long long t2 = (long long)N * 32;
    finalize_atomic<<<(int)((t2 + 255) / 256), 256, 0, stream>>>(x, out, count, N);
    return;
  }

  int* ws = (int*)d_ws;
  int* btotal = ws;            // 1024
  int* bbase = ws + 1024;      // NB+1 (<=1025, pad 1056)
  int* gcursor = ws + 2080;    // 1024
  int* packed = ws + 3104;     // E

  hipMemsetAsync(btotal, 0, 1024 * sizeof(int), stream);

  int B3 = (E + CH - 1) / CH;
  bucket_totals<<<B3, 256, 0, stream>>>(es, btotal, NB, E);
  scan_buckets<<<1, 256, 0, stream>>>(btotal, bbase, gcursor, NB, E);
  bucket_scatter<<<B3, 256, 0, stream>>>(es, gcursor, packed, NB, E);
  bucket_reduce<<<NB, 256, 0, stream>>>(x, packed, bbase, out, N);
}

// Round 6
// 175.932 us; speedup vs baseline: 3.2798x; 3.2798x over previous
//
#include <hip/hip_runtime.h>

#define D 64
#define SH 7            // 128 cols per bucket
#define CPB 128         // cols per bucket
#define CH 4096         // edges per block in bucketing kernels

// ---------- bucket-sort path ----------

__global__ __launch_bounds__(256) void bucket_totals(
    const int* __restrict__ es, int* __restrict__ btotal, int NB, int E) {
  __shared__ int h[1024];
  for (int i = threadIdx.x; i < 1024; i += 256) h[i] = 0;
  __syncthreads();
  int e0 = blockIdx.x * CH + threadIdx.x;
#pragma unroll
  for (int j = 0; j < 16; j++) {
    int e = e0 + j * 256;
    if (e < E) atomicAdd(&h[es[e] >> SH], 1);
  }
  __syncthreads();
  for (int i = threadIdx.x; i < NB; i += 256) {
    int v = h[i];
    if (v) atomicAdd(&btotal[i], v);
  }
}

// single block: exclusive scan of NB (<=1024) bucket totals
__global__ __launch_bounds__(256) void scan_buckets(
    const int* __restrict__ btotal, int* __restrict__ bbase,
    int* __restrict__ gcursor, int* __restrict__ offsets, int NB, int N, int E) {
  __shared__ int lds[256];
  int t = threadIdx.x;
  int v[4], s = 0;
#pragma unroll
  for (int i = 0; i < 4; i++) {
    int idx = t * 4 + i;
    v[i] = (idx < NB) ? btotal[idx] : 0;
    s += v[i];
  }
  lds[t] = s;
  __syncthreads();
  for (int off = 1; off < 256; off <<= 1) {
    int val = (t >= off) ? lds[t - off] : 0;
    __syncthreads();
    lds[t] += val;
    __syncthreads();
  }
  int run = (t == 0) ? 0 : lds[t - 1];
#pragma unroll
  for (int i = 0; i < 4; i++) {
    int idx = t * 4 + i;
    if (idx < NB) { bbase[idx] = run; gcursor[idx] = run; }
    run += v[i];
  }
  if (t == 0) { bbase[NB] = E; offsets[N] = E; }
}

__global__ __launch_bounds__(256) void bucket_scatter(
    const int* __restrict__ es, int* __restrict__ gcursor,
    int* __restrict__ packed, int NB, int E) {
  __shared__ int lhist[1024];   // hist -> local start -> intra-block cursor
  __shared__ int delta[1024];   // global_base - local_start per bucket
  __shared__ int sctmp[256];
  __shared__ int staged[CH];
  __shared__ int destg[CH];
  int t = threadIdx.x;
  for (int i = t; i < 1024; i += 256) lhist[i] = 0;
  __syncthreads();
  int base_e = blockIdx.x * CH;
  // pass A: local histogram
#pragma unroll
  for (int j = 0; j < 16; j++) {
    int e = base_e + t + j * 256;
    if (e < E) atomicAdd(&lhist[es[e] >> SH], 1);
  }
  __syncthreads();
  // local exclusive scan over 1024 buckets (thread owns 4)
  int v[4], s = 0;
#pragma unroll
  for (int i = 0; i < 4; i++) { v[i] = lhist[t * 4 + i]; s += v[i]; }
  sctmp[t] = s;
  __syncthreads();
  for (int off = 1; off < 256; off <<= 1) {
    int val = (t >= off) ? sctmp[t - off] : 0;
    __syncthreads();
    sctmp[t] += val;
    __syncthreads();
  }
  int run = (t == 0) ? 0 : sctmp[t - 1];
  int lstart4[4];
#pragma unroll
  for (int i = 0; i < 4; i++) { lstart4[i] = run; run += v[i]; }
  __syncthreads();  // all reads of lhist done before overwrite
  // reserve global space per bucket; set up cursor + delta
#pragma unroll
  for (int i = 0; i < 4; i++) {
    int b = t * 4 + i;
    int gb = (b < NB && v[i] > 0) ? atomicAdd(&gcursor[b], v[i]) : 0;
    delta[b] = gb - lstart4[i];
    lhist[b] = lstart4[i];
  }
  __syncthreads();
  // pass B: rank + stage (packed word: row<<7 | col_local, 24 bits)
#pragma unroll
  for (int j = 0; j < 16; j++) {
    int e = base_e + t + j * 256;
    if (e < E) {
      int c = es[e];
      int r = es[E + e];
      int b = c >> SH;
      int rank = atomicAdd(&lhist[b], 1);
      staged[rank] = (r << SH) | (c & (CPB - 1));
      destg[rank] = delta[b] + rank;
    }
  }
  __syncthreads();
  // coalesced run-contiguous write-out
  int nloc = min(CH, E - base_e);
  for (int i = t; i < nloc; i += 256) packed[destg[i]] = staged[i];
}

// one block per bucket: counting-sort the bucket's run by exact column,
// emitting CSR offsets + sorted_rows. All writes land in a block-private
// ~5KB window -> full-line write-back, no cross-XCD line sharing.
__global__ __launch_bounds__(256) void bucket_sort_cols(
    const int* __restrict__ packed, const int* __restrict__ bbase,
    int* __restrict__ offsets, int* __restrict__ sorted_rows, int N) {
  __shared__ int cnt[CPB];
  __shared__ int sc[CPB];
  __shared__ int cur[CPB];
  int b = blockIdx.x;
  int t = threadIdx.x;
  int s = bbase[b], e = bbase[b + 1];
  if (t < CPB) cnt[t] = 0;
  __syncthreads();
  for (int i = s + t; i < e; i += 256) atomicAdd(&cnt[packed[i] & (CPB - 1)], 1);
  __syncthreads();
  int v = (t < CPB) ? cnt[t] : 0;
  if (t < CPB) sc[t] = v;
  __syncthreads();
  for (int off = 1; off < CPB; off <<= 1) {
    int val = (t < CPB && t >= off) ? sc[t - off] : 0;
    __syncthreads();
    if (t < CPB) sc[t] += val;
    __syncthreads();
  }
  if (t < CPB) {
    int excl = sc[t] - v;
    cur[t] = excl;
    int gc = (b << SH) + t;
    if (gc < N) offsets[gc] = s + excl;
  }
  __syncthreads();
  for (int i = s + t; i < e; i += 256) {
    int p = packed[i];
    int c = p & (CPB - 1);
    int rank = atomicAdd(&cur[c], 1);
    sorted_rows[s + rank] = p >> SH;
  }
}

// one 64-lane wave per node; 4 lane-groups of 16, each group owns one edge,
// lane reads one float4 of the 64-float row; 16 edges in flight (4 accs)
__global__ __launch_bounds__(256) void node_reduce(
    const float4* __restrict__ x4, const int* __restrict__ sorted_rows,
    const int* __restrict__ offsets, float* __restrict__ out, int N) {
  int gid = blockIdx.x * 256 + threadIdx.x;
  int node = gid >> 6;
  if (node >= N) return;
  int lane = threadIdx.x & 63;
  int eg = lane >> 4;
  int d16 = lane & 15;
  int start = offsets[node];
  int cnt = offsets[node + 1] - start;
  float4 a0 = make_float4(0.f, 0.f, 0.f, 0.f);
  float4 a1 = make_float4(0.f, 0.f, 0.f, 0.f);
  float4 a2 = make_float4(0.f, 0.f, 0.f, 0.f);
  float4 a3 = make_float4(0.f, 0.f, 0.f, 0.f);
  for (int base = 0; base < cnt; base += 16) {
    int k0 = base + eg;
    int k1 = base + 4 + eg;
    int k2 = base + 8 + eg;
    int k3 = base + 12 + eg;
    int r0 = (k0 < cnt) ? sorted_rows[start + k0] : -1;
    int r1 = (k1 < cnt) ? sorted_rows[start + k1] : -1;
    int r2 = (k2 < cnt) ? sorted_rows[start + k2] : -1;
    int r3 = (k3 < cnt) ? sorted_rows[start + k3] : -1;
    if (r0 >= 0) { float4 v = x4[(size_t)r0 * 16 + d16];
      a0.x += v.x; a0.y += v.y; a0.z += v.z; a0.w += v.w; }
    if (r1 >= 0) { float4 v = x4[(size_t)r1 * 16 + d16];
      a1.x += v.x; a1.y += v.y; a1.z += v.z; a1.w += v.w; }
    if (r2 >= 0) { float4 v = x4[(size_t)r2 * 16 + d16];
      a2.x += v.x; a2.y += v.y; a2.z += v.z; a2.w += v.w; }
    if (r3 >= 0) { float4 v = x4[(size_t)r3 * 16 + d16];
      a3.x += v.x; a3.y += v.y; a3.z += v.z; a3.w += v.w; }
  }
  a0.x += a1.x + a2.x + a3.x;
  a0.y += a1.y + a2.y + a3.y;
  a0.z += a1.z + a2.z + a3.z;
  a0.w += a1.w + a2.w + a3.w;
  a0.x += __shfl_xor(a0.x, 16); a0.y += __shfl_xor(a0.y, 16);
  a0.z += __shfl_xor(a0.z, 16); a0.w += __shfl_xor(a0.w, 16);
  a0.x += __shfl_xor(a0.x, 32); a0.y += __shfl_xor(a0.y, 32);
  a0.z += __shfl_xor(a0.z, 32); a0.w += __shfl_xor(a0.w, 32);
  float4* o4 = (float4*)(out + (size_t)node * 2 * D);
  if (eg == 0) {
    float inv = 1.0f / (float)(cnt > 0 ? cnt : 1);
    a0.x *= inv; a0.y *= inv; a0.z *= inv; a0.w *= inv;
    o4[d16] = a0;
  } else if (eg == 1) {
    float4 v = (cnt > 0) ? x4[(size_t)node * 16 + d16]
                         : make_float4(0.f, 0.f, 0.f, 0.f);
    o4[16 + d16] = v;
  }
}

// ---------- fallback atomic path (only if ws too small) ----------

__global__ __launch_bounds__(256) void edge_scatter_atomic(
    const int* __restrict__ es, const float* __restrict__ x,
    float* __restrict__ out, int* __restrict__ count, int E) {
  int gid = blockIdx.x * blockDim.x + threadIdx.x;
  int e = gid >> 6;
  int lane = gid & 63;
  if (e >= E) return;
  int c = es[e];
  int r = es[E + e];
  if (lane == 0) atomicAdd(&count[c], 1);
  float v = x[(size_t)r * D + lane];
  unsafeAtomicAdd(&out[(size_t)c * 2 * D + lane], v);
}

__global__ __launch_bounds__(256) void finalize_atomic(
    const float* __restrict__ x, float* __restrict__ out,
    const int* __restrict__ count, int N) {
  int gid = blockIdx.x * blockDim.x + threadIdx.x;
  int node = gid >> 5;
  int j4 = gid & 31;
  if (node >= N) return;
  int cnt = count[node];
  float4* out4 = (float4*)(out + (size_t)node * 2 * D);
  if (j4 < 16) {
    float4 s = out4[j4];
    float inv = 1.0f / (float)(cnt > 0 ? cnt : 1);
    s.x *= inv; s.y *= inv; s.z *= inv; s.w *= inv;
    out4[j4] = s;
  } else {
    float4 v;
    if (cnt > 0) {
      const float4* x4 = (const float4*)(x + (size_t)node * D);
      v = x4[j4 - 16];
    } else {
      v = make_float4(0.f, 0.f, 0.f, 0.f);
    }
    out4[j4] = v;
  }
}

extern "C" void kernel_launch(void* const* d_in, const int* in_sizes, int n_in,
                              void* d_out, int out_size, void* d_ws, size_t ws_size,
                              hipStream_t stream) {
  const float* x = (const float*)d_in[0];
  const int* es = (const int*)d_in[1];
  int N = in_sizes[0] / D;
  int E = in_sizes[1] / 2;
  float* out = (float*)d_out;

  int NB = (N + CPB - 1) >> SH;
  size_t need = ((size_t)3104 + (N + 1) + (size_t)2 * E) * sizeof(int);
  if (NB > 1024 || (1 << SH) * 131072 <= N || ws_size < need) {
    int* count = (int*)d_ws;
    hipMemsetAsync(count, 0, (size_t)N * sizeof(int), stream);
    hipMemsetAsync(out, 0, (size_t)N * 2 * D * sizeof(float), stream);
    long long t1 = (long long)E * 64;
    edge_scatter_atomic<<<(int)((t1 + 255) / 256), 256, 0, stream>>>(es, x, out, count, E);
    long long t2 = (long long)N * 32;
    finalize_atomic<<<(int)((t2 + 255) / 256), 256, 0, stream>>>(x, out, count, N);
    return;
  }

  int* ws = (int*)d_ws;
  int* btotal = ws;                 // 1024
  int* bbase = ws + 1024;           // NB+1 (pad to 1056)
  int* gcursor = ws + 2080;         // 1024
  int* offsets = ws + 3104;         // N+1
  int* packed = offsets + N + 1;    // E
  int* sorted_rows = packed + E;    // E

  hipMemsetAsync(btotal, 0, 1024 * sizeof(int), stream);

  int B3 = (E + CH - 1) / CH;
  bucket_totals<<<B3, 256, 0, stream>>>(es, btotal, NB, E);
  scan_buckets<<<1, 256, 0, stream>>>(btotal, bbase, gcursor, offsets, NB, N, E);
  bucket_scatter<<<B3, 256, 0, stream>>>(es, gcursor, packed, NB, E);
  bucket_sort_cols<<<NB, 256, 0, stream>>>(packed, bbase, offsets, sorted_rows, N);

  long long rt = (long long)N * 64;
  node_reduce<<<(int)((rt + 255) / 256), 256, 0, stream>>>(
      (const float4*)x, sorted_rows, offsets, out, N);
}